// Round 1
// baseline (3566.901 us; speedup 1.0000x reference)
//
#include <hip/hip_runtime.h>

// ---------------------------------------------------------------------------
// MoEPredictor on MI355X (gfx950) — Round 0: dense bf16-MFMA baseline.
//
// Pipeline (all on `stream`, graph-capture safe):
//   1. cast x, W_in, Wg, Wu, Wd, W_out to bf16 in d_ws
//   2. hpre = x @ W_in^T          (bf16 MFMA GEMM, f32 out)
//   3. hb   = rmsnorm(hpre)*w     (also exports invrms per row)
//   4. Wr2  = (Wr*in_norm_w)@W_in (fp32 fold: router logits = invrms * x@Wr2^T;
//                                  per-row scale preserves top-k order, so
//                                  selection is fp32-exact vs the reference)
//   5. router: top-2 + softmax gates (dense N x 8, zeros elsewhere)
//   6. per expert e: G = hb@Wg[e]^T, U = hb@Wu[e]^T (bf16 out),
//                    G = silu(G)*U, oe = G@Wd[e]^T (f32 out),
//                    acc (+)= gates[:,e] * rmsnorm(oe)*enorm_w[e]
//   7. yb = rmsnorm(acc)*out_norm_w;  d_out = yb @ W_out^T (f32 out)
// ---------------------------------------------------------------------------

#define NT      8192
#define DMODEL  1024
#define DFF     4096
#define NEXP    8
#define RMS_EPS 1.1920928955078125e-07f  // jnp.finfo(float32).eps

typedef __attribute__((ext_vector_type(8))) short bf16x8;   // MFMA A/B frag (4 VGPRs)
typedef __attribute__((ext_vector_type(4))) float f32x4;    // MFMA C/D frag

__device__ __forceinline__ float bf2f(unsigned short u) {
  union { unsigned int i; float f; } c; c.i = ((unsigned int)u) << 16; return c.f;
}
__device__ __forceinline__ unsigned short f2bf(float f) {
  union { float f; unsigned int i; } c; c.f = f;
  unsigned int x = c.i;
  return (unsigned short)((x + 0x7FFFu + ((x >> 16) & 1u)) >> 16);  // RNE
}

// ---- elementwise f32 -> bf16 cast ----
__global__ __launch_bounds__(256) void cast_bf16_kernel(
    const float* __restrict__ src, unsigned short* __restrict__ dst, long n) {
  long i = ((long)blockIdx.x * 256 + threadIdx.x) * 4;
  const long stride = (long)gridDim.x * 1024;
  for (; i < n; i += stride) {
    float4 v = *(const float4*)(src + i);
    ushort4 o;
    o.x = f2bf(v.x); o.y = f2bf(v.y); o.z = f2bf(v.z); o.w = f2bf(v.w);
    *(ushort4*)(dst + i) = o;
  }
}

// ---- async global->LDS 16B (wave-uniform base + lane*16 layout) ----
__device__ __forceinline__ void async_cp16(const void* g, void* l) {
  __builtin_amdgcn_global_load_lds((const __attribute__((address_space(1))) void*)g,
                                   (__attribute__((address_space(3))) void*)l, 16, 0, 0);
}

// ---- bf16 GEMM: C[M,N] = A[M,K] @ B[N,K]^T ; m97-style 128x128x32 tile ----
// 256 threads = 4 waves in a 2x2 grid, each wave computes 64x64 via 4x4 MFMA
// 16x16x32 tiles. A/B staged via global_load_lds dwordx4 (no LDS padding —
// wave-uniform-base constraint). M,N,K all multiples of 128/128/32 here.
template <int WRITE_BF16>
__global__ __launch_bounds__(256) void gemm_bt(
    const unsigned short* __restrict__ A,  // M x K (bf16)
    const unsigned short* __restrict__ B,  // N x K (bf16)
    void* __restrict__ Cv,                 // M x N (f32 or bf16)
    int M, int N, int K) {
  __shared__ __align__(16) unsigned short As[128 * 32];
  __shared__ __align__(16) unsigned short Bs[128 * 32];
  const int tid  = threadIdx.x;
  const int lane = tid & 63;
  const int wave = tid >> 6;
  const int wm = (wave >> 1) << 6;  // wave row offset: 0 / 64
  const int wn = (wave & 1) << 6;   // wave col offset: 0 / 64
  const int lm = lane & 15;         // A-row / B-row / C-col within 16-tile
  const int kq = lane >> 4;         // k quad: k offset = kq*8

  const long arow = (long)blockIdx.x * 128;
  const long brow = (long)blockIdx.y * 128;

  // Staging: 512 chunks of 16B per tile (128 rows x 4 chunks); 2 per thread.
  const int c0 = tid, c1 = 256 + tid;
  const unsigned short* a0 = A + (arow + (c0 >> 2)) * (long)K + ((c0 & 3) << 3);
  const unsigned short* a1 = A + (arow + (c1 >> 2)) * (long)K + ((c1 & 3) << 3);
  const unsigned short* b0 = B + (brow + (c0 >> 2)) * (long)K + ((c0 & 3) << 3);
  const unsigned short* b1 = B + (brow + (c1 >> 2)) * (long)K + ((c1 & 3) << 3);
  unsigned short* la0 = As + c0 * 8;
  unsigned short* la1 = As + c1 * 8;
  unsigned short* lb0 = Bs + c0 * 8;
  unsigned short* lb1 = Bs + c1 * 8;

  f32x4 acc[4][4];
#pragma unroll
  for (int i = 0; i < 4; ++i)
#pragma unroll
    for (int j = 0; j < 4; ++j) acc[i][j] = (f32x4){0.f, 0.f, 0.f, 0.f};

  for (int k0 = 0; k0 < K; k0 += 32) {
    async_cp16(a0 + k0, la0);
    async_cp16(a1 + k0, la1);
    async_cp16(b0 + k0, lb0);
    async_cp16(b1 + k0, lb1);
    __syncthreads();  // compiler emits s_waitcnt vmcnt(0) before s_barrier

    bf16x8 af[4], bfr[4];
#pragma unroll
    for (int t = 0; t < 4; ++t)
      af[t] = *(const bf16x8*)(As + (wm + t * 16 + lm) * 32 + kq * 8);
#pragma unroll
    for (int t = 0; t < 4; ++t)
      bfr[t] = *(const bf16x8*)(Bs + (wn + t * 16 + lm) * 32 + kq * 8);
#pragma unroll
    for (int i = 0; i < 4; ++i)
#pragma unroll
      for (int j = 0; j < 4; ++j)
        acc[i][j] = __builtin_amdgcn_mfma_f32_16x16x32_bf16(af[i], bfr[j],
                                                            acc[i][j], 0, 0, 0);
    __syncthreads();
  }

  // C/D layout (measured m89/m91): col = lane&15, row = (lane>>4)*4 + reg
  const long rbase = arow + wm + kq * 4;
  const long cbase = brow + wn + lm;
#pragma unroll
  for (int i = 0; i < 4; ++i)
#pragma unroll
    for (int j = 0; j < 4; ++j)
#pragma unroll
      for (int r = 0; r < 4; ++r) {
        const long row = rbase + i * 16 + r;
        const long col = cbase + j * 16;
        const float v = acc[i][j][r];
        if (WRITE_BF16) ((unsigned short*)Cv)[row * N + col] = f2bf(v);
        else            ((float*)Cv)[row * N + col] = v;
      }
}

// ---- rmsnorm: f32 in -> bf16 out, optional invrms export; D = 1024 ----
__global__ __launch_bounds__(256) void rmsnorm_kernel(
    const float* __restrict__ in, const float* __restrict__ w,
    unsigned short* __restrict__ out, float* __restrict__ invrms) {
  const int row = blockIdx.x;
  const int tid = threadIdx.x;
  const float4 xv = ((const float4*)(in + (long)row * DMODEL))[tid];
  float ss = xv.x * xv.x + xv.y * xv.y + xv.z * xv.z + xv.w * xv.w;
#pragma unroll
  for (int o = 32; o > 0; o >>= 1) ss += __shfl_xor(ss, o);
  __shared__ float red[4];
  if ((tid & 63) == 0) red[tid >> 6] = ss;
  __syncthreads();
  const float tot = red[0] + red[1] + red[2] + red[3];
  const float s = rsqrtf(tot * (1.f / DMODEL) + RMS_EPS);
  if (invrms != nullptr && tid == 0) invrms[row] = s;
  const float4 wv = ((const float4*)w)[tid];
  ushort4 o4;
  o4.x = f2bf(xv.x * s * wv.x);
  o4.y = f2bf(xv.y * s * wv.y);
  o4.z = f2bf(xv.z * s * wv.z);
  o4.w = f2bf(xv.w * s * wv.w);
  ((ushort4*)(out + (long)row * DMODEL))[tid] = o4;
}

// ---- fold router weight through W_in: Wr2[e,k] = sum_j Wr[e,j]*nw[j]*W_in[j,k]
__global__ __launch_bounds__(256) void router_prep_kernel(
    const float* __restrict__ Wr, const float* __restrict__ nw,
    const float* __restrict__ W_in, float* __restrict__ Wr2) {
  __shared__ float wr[NEXP * DMODEL];  // 32 KB
  const int tid = threadIdx.x;
  for (int i = tid; i < NEXP * DMODEL; i += 256) wr[i] = Wr[i] * nw[i & (DMODEL - 1)];
  __syncthreads();
  const int kl = tid & 127;
  const int eb = (tid >> 7) * 4;  // e in {eb..eb+3}
  const int kg = blockIdx.x * 128 + kl;
  float a0 = 0.f, a1 = 0.f, a2 = 0.f, a3 = 0.f;
  for (int j = 0; j < DMODEL; ++j) {
    const float wij = W_in[(long)j * DMODEL + kg];  // coalesced across lanes
    a0 += wr[(eb + 0) * DMODEL + j] * wij;
    a1 += wr[(eb + 1) * DMODEL + j] * wij;
    a2 += wr[(eb + 2) * DMODEL + j] * wij;
    a3 += wr[(eb + 3) * DMODEL + j] * wij;
  }
  Wr2[(eb + 0) * DMODEL + kg] = a0;
  Wr2[(eb + 1) * DMODEL + kg] = a1;
  Wr2[(eb + 2) * DMODEL + kg] = a2;
  Wr2[(eb + 3) * DMODEL + kg] = a3;
}

// ---- router: fp32 logits from x@Wr2^T, scaled by invrms; top-2 + softmax ----
__global__ __launch_bounds__(64) void router_kernel(
    const float* __restrict__ x, const float* __restrict__ Wr2,
    const float* __restrict__ bias, const float* __restrict__ invrms,
    float* __restrict__ gates) {
  const int row = blockIdx.x;
  const int lane = threadIdx.x;
  const float* xr = x + (long)row * DMODEL;
  float p[NEXP] = {0.f, 0.f, 0.f, 0.f, 0.f, 0.f, 0.f, 0.f};
  for (int k = lane; k < DMODEL; k += 64) {
    const float xv = xr[k];
#pragma unroll
    for (int e = 0; e < NEXP; ++e) p[e] += xv * Wr2[e * DMODEL + k];
  }
#pragma unroll
  for (int o = 32; o > 0; o >>= 1)
#pragma unroll
    for (int e = 0; e < NEXP; ++e) p[e] += __shfl_xor(p[e], o);
  if (lane == 0) {
    const float s = invrms[row];
    float logit[NEXP];
    float b0 = -1e30f, b1 = -1e30f;
    int i0 = 0, i1 = 0;
#pragma unroll
    for (int e = 0; e < NEXP; ++e) {
      logit[e] = p[e] * s;
      const float be = logit[e] + bias[e];
      if (be > b0)      { b1 = b0; i1 = i0; b0 = be; i0 = e; }
      else if (be > b1) { b1 = be; i1 = e; }
    }
    const float l0 = logit[i0], l1 = logit[i1];
    const float m = fmaxf(l0, l1);
    const float e0 = expf(l0 - m), e1 = expf(l1 - m);
    const float inv = 1.f / (e0 + e1);
    float g[NEXP] = {0.f, 0.f, 0.f, 0.f, 0.f, 0.f, 0.f, 0.f};
    g[i0] = e0 * inv;
    g[i1] = e1 * inv;
#pragma unroll
    for (int e = 0; e < NEXP; ++e) gates[row * NEXP + e] = g[e];
  }
}

// ---- G = silu(G) * U  (bf16 in-place on G) ----
__global__ __launch_bounds__(256) void silu_mul_kernel(
    unsigned short* __restrict__ G, const unsigned short* __restrict__ U, long n) {
  long i = ((long)blockIdx.x * 256 + threadIdx.x) * 4;
  const long stride = (long)gridDim.x * 1024;
  for (; i < n; i += stride) {
    const ushort4 g4 = *(const ushort4*)(G + i);
    const ushort4 u4 = *(const ushort4*)(U + i);
    const float g0 = bf2f(g4.x), g1 = bf2f(g4.y), g2 = bf2f(g4.z), g3 = bf2f(g4.w);
    const float r0 = g0 / (1.f + expf(-g0)) * bf2f(u4.x);
    const float r1 = g1 / (1.f + expf(-g1)) * bf2f(u4.y);
    const float r2 = g2 / (1.f + expf(-g2)) * bf2f(u4.z);
    const float r3 = g3 / (1.f + expf(-g3)) * bf2f(u4.w);
    ushort4 o;
    o.x = f2bf(r0); o.y = f2bf(r1); o.z = f2bf(r2); o.w = f2bf(r3);
    *(ushort4*)(G + i) = o;
  }
}

// ---- acc (+)= gates[:,e] * rmsnorm(oe)*enorm_w[e] ----
__global__ __launch_bounds__(256) void expert_out_kernel(
    const float* __restrict__ oe, const float* __restrict__ enw,
    const float* __restrict__ gates, int e, float* __restrict__ acc,
    int accumulate) {
  const int row = blockIdx.x;
  const float g = gates[row * NEXP + e];
  if (accumulate && g == 0.f) return;  // block-uniform branch
  const int tid = threadIdx.x;
  const float4 xv = ((const float4*)(oe + (long)row * DMODEL))[tid];
  float ss = xv.x * xv.x + xv.y * xv.y + xv.z * xv.z + xv.w * xv.w;
#pragma unroll
  for (int o = 32; o > 0; o >>= 1) ss += __shfl_xor(ss, o);
  __shared__ float red[4];
  if ((tid & 63) == 0) red[tid >> 6] = ss;
  __syncthreads();
  const float tot = red[0] + red[1] + red[2] + red[3];
  const float s = rsqrtf(tot * (1.f / DMODEL) + RMS_EPS) * g;
  const float4 wv = ((const float4*)enw)[tid];
  float4* ap = (float4*)(acc + (long)row * DMODEL) + tid;
  float4 v;
  v.x = xv.x * s * wv.x;
  v.y = xv.y * s * wv.y;
  v.z = xv.z * s * wv.z;
  v.w = xv.w * s * wv.w;
  if (accumulate) {
    const float4 a = *ap;
    v.x += a.x; v.y += a.y; v.z += a.z; v.w += a.w;
  }
  *ap = v;
}

extern "C" void kernel_launch(void* const* d_in, const int* in_sizes, int n_in,
                              void* d_out, int out_size, void* d_ws, size_t ws_size,
                              hipStream_t stream) {
  (void)in_sizes; (void)n_in; (void)out_size; (void)ws_size;
  const float* s_in  = (const float*)d_in[0];
  const float* W_in  = (const float*)d_in[1];
  const float* innw  = (const float*)d_in[2];
  const float* Wr    = (const float*)d_in[3];
  const float* ebias = (const float*)d_in[4];
  const float* Wg    = (const float*)d_in[5];
  const float* Wu    = (const float*)d_in[6];
  const float* Wd    = (const float*)d_in[7];
  const float* enw   = (const float*)d_in[8];
  const float* outnw = (const float*)d_in[9];
  const float* W_out = (const float*)d_in[10];
  float* out = (float*)d_out;

  // ---- workspace layout (~491 MB) ----
  char* base = (char*)d_ws;
  size_t off = 0;
  auto alloc = [&](size_t bytes) -> char* {
    char* p = base + off;
    off += (bytes + 255) & ~(size_t)255;
    return p;
  };
  unsigned short* xb    = (unsigned short*)alloc((size_t)NT * DMODEL * 2);
  unsigned short* Winb  = (unsigned short*)alloc((size_t)DMODEL * DMODEL * 2);
  unsigned short* Wgb   = (unsigned short*)alloc((size_t)NEXP * DFF * DMODEL * 2);
  unsigned short* Wub   = (unsigned short*)alloc((size_t)NEXP * DFF * DMODEL * 2);
  unsigned short* Wdb   = (unsigned short*)alloc((size_t)NEXP * DMODEL * DFF * 2);
  unsigned short* Woutb = (unsigned short*)alloc((size_t)DMODEL * DMODEL * 2);
  float*          hpre  = (float*)alloc((size_t)NT * DMODEL * 4);
  unsigned short* hb    = (unsigned short*)alloc((size_t)NT * DMODEL * 2);
  float*          invr  = (float*)alloc((size_t)NT * 4);
  float*          gates = (float*)alloc((size_t)NT * NEXP * 4);
  float*          Wr2   = (float*)alloc((size_t)NEXP * DMODEL * 4);
  unsigned short* Gb    = (unsigned short*)alloc((size_t)NT * DFF * 2);
  unsigned short* Ub    = (unsigned short*)alloc((size_t)NT * DFF * 2);
  float*          oe    = (float*)alloc((size_t)NT * DMODEL * 4);
  float*          accb  = (float*)alloc((size_t)NT * DMODEL * 4);
  unsigned short* yb    = (unsigned short*)alloc((size_t)NT * DMODEL * 2);

  // ---- 1. casts ----
  cast_bf16_kernel<<<2048, 256, 0, stream>>>(s_in, xb, (long)NT * DMODEL);
  cast_bf16_kernel<<<2048, 256, 0, stream>>>(W_in, Winb, (long)DMODEL * DMODEL);
  cast_bf16_kernel<<<2048, 256, 0, stream>>>(Wg, Wgb, (long)NEXP * DFF * DMODEL);
  cast_bf16_kernel<<<2048, 256, 0, stream>>>(Wu, Wub, (long)NEXP * DFF * DMODEL);
  cast_bf16_kernel<<<2048, 256, 0, stream>>>(Wd, Wdb, (long)NEXP * DMODEL * DFF);
  cast_bf16_kernel<<<2048, 256, 0, stream>>>(W_out, Woutb, (long)DMODEL * DMODEL);

  // ---- 2. hpre = x @ W_in^T (f32 out) ----
  gemm_bt<0><<<dim3(NT / 128, DMODEL / 128), 256, 0, stream>>>(
      xb, Winb, hpre, NT, DMODEL, DMODEL);

  // ---- 3. hb = rmsnorm(hpre)*innw, export invrms ----
  rmsnorm_kernel<<<NT, 256, 0, stream>>>(hpre, innw, hb, invr);

  // ---- 4/5. router (fp32-accurate top-k) ----
  router_prep_kernel<<<DMODEL / 128, 256, 0, stream>>>(Wr, innw, W_in, Wr2);
  router_kernel<<<NT, 64, 0, stream>>>(s_in, Wr2, ebias, invr, gates);

  // ---- 6. experts (dense: gates are exactly 0 for unselected) ----
  for (int e = 0; e < NEXP; ++e) {
    const unsigned short* wg = Wgb + (size_t)e * DFF * DMODEL;
    const unsigned short* wu = Wub + (size_t)e * DFF * DMODEL;
    const unsigned short* wd = Wdb + (size_t)e * DMODEL * DFF;
    gemm_bt<1><<<dim3(NT / 128, DFF / 128), 256, 0, stream>>>(
        hb, wg, Gb, NT, DFF, DMODEL);
    gemm_bt<1><<<dim3(NT / 128, DFF / 128), 256, 0, stream>>>(
        hb, wu, Ub, NT, DFF, DMODEL);
    silu_mul_kernel<<<4096, 256, 0, stream>>>(Gb, Ub, (long)NT * DFF);
    gemm_bt<0><<<dim3(NT / 128, DMODEL / 128), 256, 0, stream>>>(
        Gb, wd, oe, NT, DMODEL, DFF);
    expert_out_kernel<<<NT, 256, 0, stream>>>(
        oe, enw + (size_t)e * DMODEL, gates, e, accb, e > 0 ? 1 : 0);
  }

  // ---- 7. output projection ----
  rmsnorm_kernel<<<NT, 256, 0, stream>>>(accb, outnw, yb, nullptr);
  gemm_bt<0><<<dim3(NT / 128, DMODEL / 128), 256, 0, stream>>>(
      yb, Woutb, out, NT, DMODEL, DMODEL);
}

// Round 2
// 2531.208 us; speedup vs baseline: 1.4092x; 1.4092x over previous
//
#include <hip/hip_runtime.h>

// ---------------------------------------------------------------------------
// MoEPredictor on MI355X (gfx950) — Round 2: top-2 compaction + fused
// gate/up/silu GEMM.
//
//   1. cast x, W_in, Wg, Wu, Wd, W_out to bf16 in d_ws
//   2. hpre = x @ W_in^T (bf16 MFMA, f32 out); hb = rmsnorm(hpre)*w (+invrms)
//   3. router: fp32 logits via folded Wr2=(Wr*nw)@W_in, top-2, softmax gates;
//      scatter token ids + gates into per-expert compact lists (atomic slots)
//   4. pad lists to 128-multiples; prefix-sum offsets (device-side)
//   5. fused GEMM per expert tile: G=hb[tok]@Wg^T, U=hb[tok]@Wu^T in one
//      block (32 MFMA/iter), epilogue silu(G)*U -> bf16 H (compact rows)
//   6. down GEMM: oe = H @ Wd^T (f32, compact rows)
//   7. per expert: acc[tok[s]] += gate[s] * rmsnorm(oe[s])*enorm_w[e]
//   8. yb = rmsnorm(acc)*out_norm_w;  d_out = yb @ W_out^T
//
// All grids static; blocks early-exit on device-side padded counts
// (graph-capture safe). Scatter is per-expert sequential => deterministic.
// ---------------------------------------------------------------------------

#define NT      8192
#define DMODEL  1024
#define DFF     4096
#define NEXP    8
#define MAXROWS (NT * 2 + NEXP * 128)  // 17408 padded compact rows max
#define RMS_EPS 1.1920928955078125e-07f  // jnp.finfo(float32).eps

typedef __attribute__((ext_vector_type(8))) short bf16x8;   // MFMA A/B frag
typedef __attribute__((ext_vector_type(4))) float f32x4;    // MFMA C/D frag

__device__ __forceinline__ float bf2f(unsigned short u) {
  union { unsigned int i; float f; } c; c.i = ((unsigned int)u) << 16; return c.f;
}
__device__ __forceinline__ unsigned short f2bf(float f) {
  union { float f; unsigned int i; } c; c.f = f;
  unsigned int x = c.i;
  return (unsigned short)((x + 0x7FFFu + ((x >> 16) & 1u)) >> 16);  // RNE
}

// ---- elementwise f32 -> bf16 cast ----
__global__ __launch_bounds__(256) void cast_bf16_kernel(
    const float* __restrict__ src, unsigned short* __restrict__ dst, long n) {
  long i = ((long)blockIdx.x * 256 + threadIdx.x) * 4;
  const long stride = (long)gridDim.x * 1024;
  for (; i < n; i += stride) {
    float4 v = *(const float4*)(src + i);
    ushort4 o;
    o.x = f2bf(v.x); o.y = f2bf(v.y); o.z = f2bf(v.z); o.w = f2bf(v.w);
    *(ushort4*)(dst + i) = o;
  }
}

// ---- async global->LDS 16B (wave-uniform base + lane*16 layout) ----
__device__ __forceinline__ void async_cp16(const void* g, void* l) {
  __builtin_amdgcn_global_load_lds((const __attribute__((address_space(1))) void*)g,
                                   (__attribute__((address_space(3))) void*)l, 16, 0, 0);
}

// ---- dense bf16 GEMM: C[M,N] = A[M,K] @ B[N,K]^T ; 128x128x32 tile ----
template <int WRITE_BF16>
__global__ __launch_bounds__(256) void gemm_bt(
    const unsigned short* __restrict__ A,  // M x K (bf16)
    const unsigned short* __restrict__ B,  // N x K (bf16)
    void* __restrict__ Cv,                 // M x N (f32 or bf16)
    int M, int N, int K) {
  __shared__ __align__(16) unsigned short As[128 * 32];
  __shared__ __align__(16) unsigned short Bs[128 * 32];
  const int tid  = threadIdx.x;
  const int lane = tid & 63;
  const int wave = tid >> 6;
  const int wm = (wave >> 1) << 6;
  const int wn = (wave & 1) << 6;
  const int lm = lane & 15;
  const int kq = lane >> 4;

  const long arow = (long)blockIdx.x * 128;
  const long brow = (long)blockIdx.y * 128;

  const int c0 = tid, c1 = 256 + tid;
  const unsigned short* a0 = A + (arow + (c0 >> 2)) * (long)K + ((c0 & 3) << 3);
  const unsigned short* a1 = A + (arow + (c1 >> 2)) * (long)K + ((c1 & 3) << 3);
  const unsigned short* b0 = B + (brow + (c0 >> 2)) * (long)K + ((c0 & 3) << 3);
  const unsigned short* b1 = B + (brow + (c1 >> 2)) * (long)K + ((c1 & 3) << 3);
  unsigned short* la0 = As + c0 * 8;
  unsigned short* la1 = As + c1 * 8;
  unsigned short* lb0 = Bs + c0 * 8;
  unsigned short* lb1 = Bs + c1 * 8;

  f32x4 acc[4][4];
#pragma unroll
  for (int i = 0; i < 4; ++i)
#pragma unroll
    for (int j = 0; j < 4; ++j) acc[i][j] = (f32x4){0.f, 0.f, 0.f, 0.f};

  for (int k0 = 0; k0 < K; k0 += 32) {
    async_cp16(a0 + k0, la0);
    async_cp16(a1 + k0, la1);
    async_cp16(b0 + k0, lb0);
    async_cp16(b1 + k0, lb1);
    __syncthreads();

    bf16x8 af[4], bfr[4];
#pragma unroll
    for (int t = 0; t < 4; ++t)
      af[t] = *(const bf16x8*)(As + (wm + t * 16 + lm) * 32 + kq * 8);
#pragma unroll
    for (int t = 0; t < 4; ++t)
      bfr[t] = *(const bf16x8*)(Bs + (wn + t * 16 + lm) * 32 + kq * 8);
#pragma unroll
    for (int i = 0; i < 4; ++i)
#pragma unroll
      for (int j = 0; j < 4; ++j)
        acc[i][j] = __builtin_amdgcn_mfma_f32_16x16x32_bf16(af[i], bfr[j],
                                                            acc[i][j], 0, 0, 0);
    __syncthreads();
  }

  const long rbase = arow + wm + kq * 4;
  const long cbase = brow + wn + lm;
#pragma unroll
  for (int i = 0; i < 4; ++i)
#pragma unroll
    for (int j = 0; j < 4; ++j)
#pragma unroll
      for (int r = 0; r < 4; ++r) {
        const long row = rbase + i * 16 + r;
        const long col = cbase + j * 16;
        const float v = acc[i][j][r];
        if (WRITE_BF16) ((unsigned short*)Cv)[row * N + col] = f2bf(v);
        else            ((float*)Cv)[row * N + col] = v;
      }
}

// ---- fused grouped GEMM: H = silu(hb[tok] @ Wg[e]^T) * (hb[tok] @ Wu[e]^T) ----
// grid (64, DFF/128, NEXP); early-exit blocks past pcnt[e]. A rows gathered
// via tok; output rows compact at off[e].
__global__ __launch_bounds__(256) void gemm_gateup(
    const unsigned short* __restrict__ A,   // hb: NT x DMODEL
    const unsigned short* __restrict__ Wg,  // NEXP x DFF x DMODEL
    const unsigned short* __restrict__ Wu,  // NEXP x DFF x DMODEL
    unsigned short* __restrict__ H,         // MAXROWS x DFF
    const int* __restrict__ tok, const int* __restrict__ pcnt,
    const int* __restrict__ off) {
  const int e = blockIdx.z;
  const int rb = blockIdx.x;
  if (rb * 128 >= pcnt[e]) return;
  const int K = DMODEL, N = DFF;
  __shared__ __align__(16) unsigned short As[128 * 32];
  __shared__ __align__(16) unsigned short Bgs[128 * 32];
  __shared__ __align__(16) unsigned short Bus[128 * 32];
  const int tid = threadIdx.x, lane = tid & 63, wave = tid >> 6;
  const int wm = (wave >> 1) << 6, wn = (wave & 1) << 6;
  const int lm = lane & 15, kq = lane >> 4;
  const long brow = (long)blockIdx.y * 128;

  const int c0 = tid, c1 = tid + 256;
  const int r0 = c0 >> 2, r1 = c1 >> 2;
  const int o0 = (c0 & 3) << 3, o1 = (c1 & 3) << 3;
  const int tbase = e * NT + rb * 128;
  const unsigned short* a0 = A + (long)tok[tbase + r0] * K + o0;
  const unsigned short* a1 = A + (long)tok[tbase + r1] * K + o1;
  const unsigned short* wgb = Wg + (size_t)e * N * K;
  const unsigned short* wub = Wu + (size_t)e * N * K;
  const unsigned short* g0 = wgb + (brow + r0) * (long)K + o0;
  const unsigned short* g1 = wgb + (brow + r1) * (long)K + o1;
  const unsigned short* u0 = wub + (brow + r0) * (long)K + o0;
  const unsigned short* u1 = wub + (brow + r1) * (long)K + o1;
  unsigned short* la0 = As + c0 * 8;
  unsigned short* la1 = As + c1 * 8;
  unsigned short* lg0 = Bgs + c0 * 8;
  unsigned short* lg1 = Bgs + c1 * 8;
  unsigned short* lu0 = Bus + c0 * 8;
  unsigned short* lu1 = Bus + c1 * 8;

  f32x4 accg[4][4], accu[4][4];
#pragma unroll
  for (int i = 0; i < 4; ++i)
#pragma unroll
    for (int j = 0; j < 4; ++j) {
      accg[i][j] = (f32x4){0.f, 0.f, 0.f, 0.f};
      accu[i][j] = (f32x4){0.f, 0.f, 0.f, 0.f};
    }

  for (int k0 = 0; k0 < K; k0 += 32) {
    async_cp16(a0 + k0, la0);
    async_cp16(a1 + k0, la1);
    async_cp16(g0 + k0, lg0);
    async_cp16(g1 + k0, lg1);
    async_cp16(u0 + k0, lu0);
    async_cp16(u1 + k0, lu1);
    __syncthreads();

    bf16x8 af[4], bgf[4], buf[4];
#pragma unroll
    for (int t = 0; t < 4; ++t)
      af[t] = *(const bf16x8*)(As + (wm + t * 16 + lm) * 32 + kq * 8);
#pragma unroll
    for (int t = 0; t < 4; ++t)
      bgf[t] = *(const bf16x8*)(Bgs + (wn + t * 16 + lm) * 32 + kq * 8);
#pragma unroll
    for (int t = 0; t < 4; ++t)
      buf[t] = *(const bf16x8*)(Bus + (wn + t * 16 + lm) * 32 + kq * 8);
#pragma unroll
    for (int i = 0; i < 4; ++i)
#pragma unroll
      for (int j = 0; j < 4; ++j) {
        accg[i][j] = __builtin_amdgcn_mfma_f32_16x16x32_bf16(af[i], bgf[j],
                                                             accg[i][j], 0, 0, 0);
        accu[i][j] = __builtin_amdgcn_mfma_f32_16x16x32_bf16(af[i], buf[j],
                                                             accu[i][j], 0, 0, 0);
      }
    __syncthreads();
  }

  const long rbase = (long)off[e] + rb * 128 + wm + kq * 4;
  const long cbase = brow + wn + lm;
#pragma unroll
  for (int i = 0; i < 4; ++i)
#pragma unroll
    for (int j = 0; j < 4; ++j)
#pragma unroll
      for (int r = 0; r < 4; ++r) {
        const float g = accg[i][j][r];
        const float u = accu[i][j][r];
        const float h = g / (1.f + expf(-g)) * u;
        H[(rbase + i * 16 + r) * (long)N + (cbase + j * 16)] = f2bf(h);
      }
}

// ---- grouped down GEMM: oe = H @ Wd[e]^T (compact rows, f32 out) ----
__global__ __launch_bounds__(256) void gemm_down(
    const unsigned short* __restrict__ H,   // MAXROWS x DFF
    const unsigned short* __restrict__ Wd,  // NEXP x DMODEL x DFF
    float* __restrict__ oe,                 // MAXROWS x DMODEL
    const int* __restrict__ pcnt, const int* __restrict__ off) {
  const int e = blockIdx.z;
  const int rb = blockIdx.x;
  if (rb * 128 >= pcnt[e]) return;
  const int K = DFF, N = DMODEL;
  __shared__ __align__(16) unsigned short As[128 * 32];
  __shared__ __align__(16) unsigned short Bs[128 * 32];
  const int tid = threadIdx.x, lane = tid & 63, wave = tid >> 6;
  const int wm = (wave >> 1) << 6, wn = (wave & 1) << 6;
  const int lm = lane & 15, kq = lane >> 4;
  const long arow = (long)off[e] + rb * 128;
  const long brow = (long)blockIdx.y * 128;

  const int c0 = tid, c1 = 256 + tid;
  const unsigned short* a0 = H + (arow + (c0 >> 2)) * (long)K + ((c0 & 3) << 3);
  const unsigned short* a1 = H + (arow + (c1 >> 2)) * (long)K + ((c1 & 3) << 3);
  const unsigned short* wdb = Wd + (size_t)e * N * K;
  const unsigned short* b0 = wdb + (brow + (c0 >> 2)) * (long)K + ((c0 & 3) << 3);
  const unsigned short* b1 = wdb + (brow + (c1 >> 2)) * (long)K + ((c1 & 3) << 3);
  unsigned short* la0 = As + c0 * 8;
  unsigned short* la1 = As + c1 * 8;
  unsigned short* lb0 = Bs + c0 * 8;
  unsigned short* lb1 = Bs + c1 * 8;

  f32x4 acc[4][4];
#pragma unroll
  for (int i = 0; i < 4; ++i)
#pragma unroll
    for (int j = 0; j < 4; ++j) acc[i][j] = (f32x4){0.f, 0.f, 0.f, 0.f};

  for (int k0 = 0; k0 < K; k0 += 32) {
    async_cp16(a0 + k0, la0);
    async_cp16(a1 + k0, la1);
    async_cp16(b0 + k0, lb0);
    async_cp16(b1 + k0, lb1);
    __syncthreads();

    bf16x8 af[4], bfr[4];
#pragma unroll
    for (int t = 0; t < 4; ++t)
      af[t] = *(const bf16x8*)(As + (wm + t * 16 + lm) * 32 + kq * 8);
#pragma unroll
    for (int t = 0; t < 4; ++t)
      bfr[t] = *(const bf16x8*)(Bs + (wn + t * 16 + lm) * 32 + kq * 8);
#pragma unroll
    for (int i = 0; i < 4; ++i)
#pragma unroll
      for (int j = 0; j < 4; ++j)
        acc[i][j] = __builtin_amdgcn_mfma_f32_16x16x32_bf16(af[i], bfr[j],
                                                            acc[i][j], 0, 0, 0);
    __syncthreads();
  }

  const long rbase = arow + wm + kq * 4;
  const long cbase = brow + wn + lm;
#pragma unroll
  for (int i = 0; i < 4; ++i)
#pragma unroll
    for (int j = 0; j < 4; ++j)
#pragma unroll
      for (int r = 0; r < 4; ++r)
        oe[(rbase + i * 16 + r) * (long)N + (cbase + j * 16)] = acc[i][j][r];
}

// ---- rmsnorm: f32 in -> bf16 out, optional invrms export; D = 1024 ----
__global__ __launch_bounds__(256) void rmsnorm_kernel(
    const float* __restrict__ in, const float* __restrict__ w,
    unsigned short* __restrict__ out, float* __restrict__ invrms) {
  const int row = blockIdx.x;
  const int tid = threadIdx.x;
  const float4 xv = ((const float4*)(in + (long)row * DMODEL))[tid];
  float ss = xv.x * xv.x + xv.y * xv.y + xv.z * xv.z + xv.w * xv.w;
#pragma unroll
  for (int o = 32; o > 0; o >>= 1) ss += __shfl_xor(ss, o);
  __shared__ float red[4];
  if ((tid & 63) == 0) red[tid >> 6] = ss;
  __syncthreads();
  const float tot = red[0] + red[1] + red[2] + red[3];
  const float s = rsqrtf(tot * (1.f / DMODEL) + RMS_EPS);
  if (invrms != nullptr && tid == 0) invrms[row] = s;
  const float4 wv = ((const float4*)w)[tid];
  ushort4 o4;
  o4.x = f2bf(xv.x * s * wv.x);
  o4.y = f2bf(xv.y * s * wv.y);
  o4.z = f2bf(xv.z * s * wv.z);
  o4.w = f2bf(xv.w * s * wv.w);
  ((ushort4*)(out + (long)row * DMODEL))[tid] = o4;
}

// ---- fold router weight through W_in: Wr2[e,k] = sum_j Wr[e,j]*nw[j]*W_in[j,k]
__global__ __launch_bounds__(256) void router_prep_kernel(
    const float* __restrict__ Wr, const float* __restrict__ nw,
    const float* __restrict__ W_in, float* __restrict__ Wr2) {
  __shared__ float wr[NEXP * DMODEL];  // 32 KB
  const int tid = threadIdx.x;
  for (int i = tid; i < NEXP * DMODEL; i += 256) wr[i] = Wr[i] * nw[i & (DMODEL - 1)];
  __syncthreads();
  const int kl = tid & 127;
  const int eb = (tid >> 7) * 4;
  const int kg = blockIdx.x * 128 + kl;
  float a0 = 0.f, a1 = 0.f, a2 = 0.f, a3 = 0.f;
  for (int j = 0; j < DMODEL; ++j) {
    const float wij = W_in[(long)j * DMODEL + kg];
    a0 += wr[(eb + 0) * DMODEL + j] * wij;
    a1 += wr[(eb + 1) * DMODEL + j] * wij;
    a2 += wr[(eb + 2) * DMODEL + j] * wij;
    a3 += wr[(eb + 3) * DMODEL + j] * wij;
  }
  Wr2[(eb + 0) * DMODEL + kg] = a0;
  Wr2[(eb + 1) * DMODEL + kg] = a1;
  Wr2[(eb + 2) * DMODEL + kg] = a2;
  Wr2[(eb + 3) * DMODEL + kg] = a3;
}

// ---- router: fp32 logits, top-2, softmax; scatter into compact lists ----
__global__ __launch_bounds__(64) void router_kernel(
    const float* __restrict__ x, const float* __restrict__ Wr2,
    const float* __restrict__ bias, const float* __restrict__ invrms,
    int* __restrict__ cnt, int* __restrict__ tok, float* __restrict__ gv) {
  const int row = blockIdx.x;
  const int lane = threadIdx.x;
  const float* xr = x + (long)row * DMODEL;
  float p[NEXP] = {0.f, 0.f, 0.f, 0.f, 0.f, 0.f, 0.f, 0.f};
  for (int k = lane; k < DMODEL; k += 64) {
    const float xv = xr[k];
#pragma unroll
    for (int e = 0; e < NEXP; ++e) p[e] += xv * Wr2[e * DMODEL + k];
  }
#pragma unroll
  for (int o = 32; o > 0; o >>= 1)
#pragma unroll
    for (int e = 0; e < NEXP; ++e) p[e] += __shfl_xor(p[e], o);
  if (lane == 0) {
    const float s = invrms[row];
    float logit[NEXP];
    float b0 = -1e30f, b1 = -1e30f;
    int i0 = 0, i1 = 0;
#pragma unroll
    for (int e = 0; e < NEXP; ++e) {
      logit[e] = p[e] * s;
      const float be = logit[e] + bias[e];
      if (be > b0)      { b1 = b0; i1 = i0; b0 = be; i0 = e; }
      else if (be > b1) { b1 = be; i1 = e; }
    }
    const float l0 = logit[i0], l1 = logit[i1];
    const float m = fmaxf(l0, l1);
    const float e0 = expf(l0 - m), e1 = expf(l1 - m);
    const float inv = 1.f / (e0 + e1);
    const int s0 = atomicAdd(&cnt[i0], 1);
    tok[i0 * NT + s0] = row;
    gv[i0 * NT + s0] = e0 * inv;
    const int s1 = atomicAdd(&cnt[i1], 1);
    tok[i1 * NT + s1] = row;
    gv[i1 * NT + s1] = e1 * inv;
  }
}

// ---- pad counts to 128-multiples, prefix-sum offsets, fill pad slots ----
__global__ __launch_bounds__(256) void pad_kernel(
    const int* __restrict__ cnt, int* __restrict__ tok,
    int* __restrict__ pcnt, int* __restrict__ off) {
  __shared__ int sc[NEXP], sp[NEXP];
  const int tid = threadIdx.x;
  if (tid == 0) {
    int o = 0;
    for (int e = 0; e < NEXP; ++e) {
      const int c = cnt[e];
      const int p = (c + 127) & ~127;
      sc[e] = c; sp[e] = p;
      pcnt[e] = p; off[e] = o;
      o += p;
    }
    off[NEXP] = o;
  }
  __syncthreads();
  for (int e = 0; e < NEXP; ++e) {
    const int c = sc[e], p = sp[e];
    for (int s = c + tid; s < p; s += 256) tok[e * NT + s] = 0;
  }
}

// ---- acc[tok[s]] += gv[s] * rmsnorm(oe[off+s])*enorm_w[e]  (one expert) ----
__global__ __launch_bounds__(256) void expert_scatter(
    const float* __restrict__ oe, const float* __restrict__ enw,
    const int* __restrict__ tok, const float* __restrict__ gv,
    const int* __restrict__ cnt, const int* __restrict__ off,
    int e, float* __restrict__ acc) {
  const int s = blockIdx.x;
  if (s >= cnt[e]) return;
  const int row = tok[e * NT + s];
  const float g = gv[e * NT + s];
  const int tid = threadIdx.x;
  const float4 xv = ((const float4*)(oe + ((long)off[e] + s) * DMODEL))[tid];
  float ss = xv.x * xv.x + xv.y * xv.y + xv.z * xv.z + xv.w * xv.w;
#pragma unroll
  for (int o = 32; o > 0; o >>= 1) ss += __shfl_xor(ss, o);
  __shared__ float red[4];
  if ((tid & 63) == 0) red[tid >> 6] = ss;
  __syncthreads();
  const float tot = red[0] + red[1] + red[2] + red[3];
  const float sc = rsqrtf(tot * (1.f / DMODEL) + RMS_EPS) * g;
  const float4 wv = ((const float4*)enw)[tid];
  float4* ap = (float4*)(acc + (long)row * DMODEL) + tid;
  float4 a = *ap;
  a.x += xv.x * sc * wv.x;
  a.y += xv.y * sc * wv.y;
  a.z += xv.z * sc * wv.z;
  a.w += xv.w * sc * wv.w;
  *ap = a;
}

extern "C" void kernel_launch(void* const* d_in, const int* in_sizes, int n_in,
                              void* d_out, int out_size, void* d_ws, size_t ws_size,
                              hipStream_t stream) {
  (void)in_sizes; (void)n_in; (void)out_size; (void)ws_size;
  const float* s_in  = (const float*)d_in[0];
  const float* W_in  = (const float*)d_in[1];
  const float* innw  = (const float*)d_in[2];
  const float* Wr    = (const float*)d_in[3];
  const float* ebias = (const float*)d_in[4];
  const float* Wg    = (const float*)d_in[5];
  const float* Wu    = (const float*)d_in[6];
  const float* Wd    = (const float*)d_in[7];
  const float* enw   = (const float*)d_in[8];
  const float* outnw = (const float*)d_in[9];
  const float* W_out = (const float*)d_in[10];
  float* out = (float*)d_out;

  // ---- workspace layout (~475 MB, with aliasing) ----
  char* base = (char*)d_ws;
  size_t off_b = 0;
  auto alloc = [&](size_t bytes) -> char* {
    char* p = base + off_b;
    off_b += (bytes + 255) & ~(size_t)255;
    return p;
  };
  unsigned short* xb    = (unsigned short*)alloc((size_t)NT * DMODEL * 2);
  unsigned short* Winb  = (unsigned short*)alloc((size_t)DMODEL * DMODEL * 2);
  unsigned short* Wgb   = (unsigned short*)alloc((size_t)NEXP * DFF * DMODEL * 2);
  unsigned short* Wub   = (unsigned short*)alloc((size_t)NEXP * DFF * DMODEL * 2);
  unsigned short* Wdb   = (unsigned short*)alloc((size_t)NEXP * DMODEL * DFF * 2);
  unsigned short* Woutb = (unsigned short*)alloc((size_t)DMODEL * DMODEL * 2);
  float*          hpre  = (float*)alloc((size_t)NT * DMODEL * 4);
  unsigned short* hb    = (unsigned short*)alloc((size_t)NT * DMODEL * 2);
  float*          invr  = (float*)alloc((size_t)NT * 4);
  float*          Wr2   = (float*)alloc((size_t)NEXP * DMODEL * 4);
  int*            cnt   = (int*)alloc((size_t)NEXP * 4);
  int*            pcnt  = (int*)alloc((size_t)NEXP * 4);
  int*            offs  = (int*)alloc((size_t)(NEXP + 1) * 4);
  int*            tok   = (int*)alloc((size_t)NEXP * NT * 4);
  float*          gv    = (float*)alloc((size_t)NEXP * NT * 4);
  unsigned short* Hc    = (unsigned short*)alloc((size_t)MAXROWS * DFF * 2);
  float*          oec   = (float*)alloc((size_t)MAXROWS * DMODEL * 4);
  // aliases: accb over hpre (hpre dead after rmsnorm), yb over xb (dead after
  // in-projection GEMM)
  float*          accb  = hpre;
  unsigned short* yb    = xb;

  // ---- 1. casts + zero the slot counters ----
  hipMemsetAsync(cnt, 0, NEXP * 4, stream);
  cast_bf16_kernel<<<2048, 256, 0, stream>>>(s_in, xb, (long)NT * DMODEL);
  cast_bf16_kernel<<<2048, 256, 0, stream>>>(W_in, Winb, (long)DMODEL * DMODEL);
  cast_bf16_kernel<<<2048, 256, 0, stream>>>(Wg, Wgb, (long)NEXP * DFF * DMODEL);
  cast_bf16_kernel<<<2048, 256, 0, stream>>>(Wu, Wub, (long)NEXP * DFF * DMODEL);
  cast_bf16_kernel<<<2048, 256, 0, stream>>>(Wd, Wdb, (long)NEXP * DMODEL * DFF);
  cast_bf16_kernel<<<2048, 256, 0, stream>>>(W_out, Woutb, (long)DMODEL * DMODEL);

  // ---- 2. hpre = x @ W_in^T ; hb = rmsnorm(hpre)*innw (+invrms) ----
  gemm_bt<0><<<dim3(NT / 128, DMODEL / 128), 256, 0, stream>>>(
      xb, Winb, hpre, NT, DMODEL, DMODEL);
  rmsnorm_kernel<<<NT, 256, 0, stream>>>(hpre, innw, hb, invr);
  // hpre is dead now; zero its region for use as the output accumulator
  hipMemsetAsync(accb, 0, (size_t)NT * DMODEL * 4, stream);

  // ---- 3/4. router + compaction ----
  router_prep_kernel<<<DMODEL / 128, 256, 0, stream>>>(Wr, innw, W_in, Wr2);
  router_kernel<<<NT, 64, 0, stream>>>(s_in, Wr2, ebias, invr, cnt, tok, gv);
  pad_kernel<<<1, 256, 0, stream>>>(cnt, tok, pcnt, offs);

  // ---- 5. fused gate/up/silu (compact rows, gathered A) ----
  gemm_gateup<<<dim3(NT / 128, DFF / 128, NEXP), 256, 0, stream>>>(
      hb, Wgb, Wub, Hc, tok, pcnt, offs);

  // ---- 6. down projection (compact rows) ----
  gemm_down<<<dim3(NT / 128, DMODEL / 128, NEXP), 256, 0, stream>>>(
      Hc, Wdb, oec, pcnt, offs);

  // ---- 7. per-expert scatter-accumulate (sequential => deterministic) ----
  for (int e = 0; e < NEXP; ++e)
    expert_scatter<<<NT, 256, 0, stream>>>(
        oec, enw + (size_t)e * DMODEL, tok, gv, cnt, offs, e, accb);

  // ---- 8. output projection ----
  rmsnorm_kernel<<<NT, 256, 0, stream>>>(accb, outnw, yb, nullptr);
  gemm_bt<0><<<dim3(NT / 128, DMODEL / 128), 256, 0, stream>>>(
      yb, Woutb, out, NT, DMODEL, DMODEL);
}

// Round 3
// 1709.356 us; speedup vs baseline: 2.0867x; 1.4808x over previous
//
#include <hip/hip_runtime.h>

// ---------------------------------------------------------------------------
// MoEPredictor on MI355X (gfx950) — Round 3: compaction + contiguous gather +
// single-accumulator expert GEMMs (silu fused into the Up-GEMM epilogue).
//
//   1. cast x, W_in, Wg, Wu, Wd, W_out to bf16 in d_ws
//   2. hpre = x @ W_in^T (bf16 MFMA, f32 out); hb = rmsnorm(hpre)*w (+invrms)
//   3. router: fp32 logits via folded Wr2=(Wr*nw)@W_in, top-2, softmax gates;
//      scatter token ids + gates into per-expert lists; pad to 128-multiples
//   4. gather: Ac[r] = hb[tok[r]]  (compact contiguous A for all experts)
//   5. gate GEMM:  Hc = Ac @ Wg[e]^T (bf16)          [VGPR~68, 16-acc tile]
//   6. up GEMM:    Hc = silu(Hc) * (Ac @ Wu[e]^T)    [in-place epilogue fuse]
//   7. down GEMM:  oec = Hc @ Wd[e]^T (f32)
//   8. per expert: acc[tok[s]] += gate[s] * rmsnorm(oec[s])*enorm_w[e]
//   9. yb = rmsnorm(acc)*out_norm_w;  d_out = yb @ W_out^T
//
// All grids static; blocks early-exit on device-side offsets (graph-capture
// safe). Expert id per block recovered from 128-aligned segment offsets.
// ---------------------------------------------------------------------------

#define NT      8192
#define DMODEL  1024
#define DFF     4096
#define NEXP    8
#define MAXROWS (NT * 2 + NEXP * 128)  // 17408 padded compact rows max
#define RMS_EPS 1.1920928955078125e-07f  // jnp.finfo(float32).eps

typedef __attribute__((ext_vector_type(8))) short bf16x8;   // MFMA A/B frag
typedef __attribute__((ext_vector_type(4))) float f32x4;    // MFMA C/D frag

__device__ __forceinline__ float bf2f(unsigned short u) {
  union { unsigned int i; float f; } c; c.i = ((unsigned int)u) << 16; return c.f;
}
__device__ __forceinline__ unsigned short f2bf(float f) {
  union { float f; unsigned int i; } c; c.f = f;
  unsigned int x = c.i;
  return (unsigned short)((x + 0x7FFFu + ((x >> 16) & 1u)) >> 16);  // RNE
}

// ---- elementwise f32 -> bf16 cast ----
__global__ __launch_bounds__(256) void cast_bf16_kernel(
    const float* __restrict__ src, unsigned short* __restrict__ dst, long n) {
  long i = ((long)blockIdx.x * 256 + threadIdx.x) * 4;
  const long stride = (long)gridDim.x * 1024;
  for (; i < n; i += stride) {
    float4 v = *(const float4*)(src + i);
    ushort4 o;
    o.x = f2bf(v.x); o.y = f2bf(v.y); o.z = f2bf(v.z); o.w = f2bf(v.w);
    *(ushort4*)(dst + i) = o;
  }
}

// ---- async global->LDS 16B (wave-uniform base + lane*16 layout) ----
__device__ __forceinline__ void async_cp16(const void* g, void* l) {
  __builtin_amdgcn_global_load_lds((const __attribute__((address_space(1))) void*)g,
                                   (__attribute__((address_space(3))) void*)l, 16, 0, 0);
}

// ---- dense bf16 GEMM: C[M,N] = A[M,K] @ B[N,K]^T ; 128x128x32 tile ----
template <int WRITE_BF16>
__global__ __launch_bounds__(256) void gemm_bt(
    const unsigned short* __restrict__ A,  // M x K (bf16)
    const unsigned short* __restrict__ B,  // N x K (bf16)
    void* __restrict__ Cv,                 // M x N (f32 or bf16)
    int M, int N, int K) {
  __shared__ __align__(16) unsigned short As[128 * 32];
  __shared__ __align__(16) unsigned short Bs[128 * 32];
  const int tid  = threadIdx.x;
  const int lane = tid & 63;
  const int wave = tid >> 6;
  const int wm = (wave >> 1) << 6;
  const int wn = (wave & 1) << 6;
  const int lm = lane & 15;
  const int kq = lane >> 4;

  const long arow = (long)blockIdx.x * 128;
  const long brow = (long)blockIdx.y * 128;

  const int c0 = tid, c1 = 256 + tid;
  const unsigned short* a0 = A + (arow + (c0 >> 2)) * (long)K + ((c0 & 3) << 3);
  const unsigned short* a1 = A + (arow + (c1 >> 2)) * (long)K + ((c1 & 3) << 3);
  const unsigned short* b0 = B + (brow + (c0 >> 2)) * (long)K + ((c0 & 3) << 3);
  const unsigned short* b1 = B + (brow + (c1 >> 2)) * (long)K + ((c1 & 3) << 3);
  unsigned short* la0 = As + c0 * 8;
  unsigned short* la1 = As + c1 * 8;
  unsigned short* lb0 = Bs + c0 * 8;
  unsigned short* lb1 = Bs + c1 * 8;

  f32x4 acc[4][4];
#pragma unroll
  for (int i = 0; i < 4; ++i)
#pragma unroll
    for (int j = 0; j < 4; ++j) acc[i][j] = (f32x4){0.f, 0.f, 0.f, 0.f};

  for (int k0 = 0; k0 < K; k0 += 32) {
    async_cp16(a0 + k0, la0);
    async_cp16(a1 + k0, la1);
    async_cp16(b0 + k0, lb0);
    async_cp16(b1 + k0, lb1);
    __syncthreads();

    bf16x8 af[4], bfr[4];
#pragma unroll
    for (int t = 0; t < 4; ++t)
      af[t] = *(const bf16x8*)(As + (wm + t * 16 + lm) * 32 + kq * 8);
#pragma unroll
    for (int t = 0; t < 4; ++t)
      bfr[t] = *(const bf16x8*)(Bs + (wn + t * 16 + lm) * 32 + kq * 8);
#pragma unroll
    for (int i = 0; i < 4; ++i)
#pragma unroll
      for (int j = 0; j < 4; ++j)
        acc[i][j] = __builtin_amdgcn_mfma_f32_16x16x32_bf16(af[i], bfr[j],
                                                            acc[i][j], 0, 0, 0);
    __syncthreads();
  }

  const long rbase = arow + wm + kq * 4;
  const long cbase = brow + wn + lm;
#pragma unroll
  for (int i = 0; i < 4; ++i)
#pragma unroll
    for (int j = 0; j < 4; ++j)
#pragma unroll
      for (int r = 0; r < 4; ++r) {
        const long row = rbase + i * 16 + r;
        const long col = cbase + j * 16;
        const float v = acc[i][j][r];
        if (WRITE_BF16) ((unsigned short*)Cv)[row * N + col] = f2bf(v);
        else            ((float*)Cv)[row * N + col] = v;
      }
}

// ---- grouped expert GEMM on compact rows: C = A[seg] @ W[e]^T ----
// A rows are compact+contiguous (segments 128-aligned per expert, offsets in
// offs[0..NEXP]). FUSE_SILU: C already holds gate bf16 at the same tile;
// epilogue computes silu(g)*u in place.
template <int WRITE_BF16, int FUSE_SILU>
__global__ __launch_bounds__(256) void gemm_expert(
    const unsigned short* __restrict__ A,  // MAXROWS x K (compact)
    const unsigned short* __restrict__ W,  // NEXP x N x K
    void* Cv,                              // MAXROWS x N (aliases gate if FUSE_SILU)
    const int* __restrict__ offs,          // NEXP+1, 128-aligned
    int N, int K, size_t wstride) {
  const int rb = blockIdx.x;
  const int row0 = rb * 128;
  if (row0 >= offs[NEXP]) return;
  int e = 0;
#pragma unroll
  for (int i = 1; i < NEXP; ++i) e += (row0 >= offs[i]) ? 1 : 0;

  __shared__ __align__(16) unsigned short As[128 * 32];
  __shared__ __align__(16) unsigned short Bs[128 * 32];
  const int tid = threadIdx.x, lane = tid & 63, wave = tid >> 6;
  const int wm = (wave >> 1) << 6, wn = (wave & 1) << 6;
  const int lm = lane & 15, kq = lane >> 4;
  const long arow = row0;
  const long brow = (long)blockIdx.y * 128;
  const unsigned short* B = W + (size_t)e * wstride;

  const int c0 = tid, c1 = 256 + tid;
  const unsigned short* a0 = A + (arow + (c0 >> 2)) * (long)K + ((c0 & 3) << 3);
  const unsigned short* a1 = A + (arow + (c1 >> 2)) * (long)K + ((c1 & 3) << 3);
  const unsigned short* b0 = B + (brow + (c0 >> 2)) * (long)K + ((c0 & 3) << 3);
  const unsigned short* b1 = B + (brow + (c1 >> 2)) * (long)K + ((c1 & 3) << 3);
  unsigned short* la0 = As + c0 * 8;
  unsigned short* la1 = As + c1 * 8;
  unsigned short* lb0 = Bs + c0 * 8;
  unsigned short* lb1 = Bs + c1 * 8;

  f32x4 acc[4][4];
#pragma unroll
  for (int i = 0; i < 4; ++i)
#pragma unroll
    for (int j = 0; j < 4; ++j) acc[i][j] = (f32x4){0.f, 0.f, 0.f, 0.f};

  for (int k0 = 0; k0 < K; k0 += 32) {
    async_cp16(a0 + k0, la0);
    async_cp16(a1 + k0, la1);
    async_cp16(b0 + k0, lb0);
    async_cp16(b1 + k0, lb1);
    __syncthreads();

    bf16x8 af[4], bfr[4];
#pragma unroll
    for (int t = 0; t < 4; ++t)
      af[t] = *(const bf16x8*)(As + (wm + t * 16 + lm) * 32 + kq * 8);
#pragma unroll
    for (int t = 0; t < 4; ++t)
      bfr[t] = *(const bf16x8*)(Bs + (wn + t * 16 + lm) * 32 + kq * 8);
#pragma unroll
    for (int i = 0; i < 4; ++i)
#pragma unroll
      for (int j = 0; j < 4; ++j)
        acc[i][j] = __builtin_amdgcn_mfma_f32_16x16x32_bf16(af[i], bfr[j],
                                                            acc[i][j], 0, 0, 0);
    __syncthreads();
  }

  const long rbase = arow + wm + kq * 4;
  const long cbase = brow + wn + lm;
#pragma unroll
  for (int i = 0; i < 4; ++i)
#pragma unroll
    for (int j = 0; j < 4; ++j)
#pragma unroll
      for (int r = 0; r < 4; ++r) {
        const long row = rbase + i * 16 + r;
        const long col = cbase + j * 16;
        float v = acc[i][j][r];
        if (FUSE_SILU) {
          const float g = bf2f(((const unsigned short*)Cv)[row * N + col]);
          v = g / (1.f + expf(-g)) * v;
        }
        if (WRITE_BF16) ((unsigned short*)Cv)[row * N + col] = f2bf(v);
        else            ((float*)Cv)[row * N + col] = v;
      }
}

// ---- rmsnorm: f32 in -> bf16 out, optional invrms export; D = 1024 ----
__global__ __launch_bounds__(256) void rmsnorm_kernel(
    const float* __restrict__ in, const float* __restrict__ w,
    unsigned short* __restrict__ out, float* __restrict__ invrms) {
  const int row = blockIdx.x;
  const int tid = threadIdx.x;
  const float4 xv = ((const float4*)(in + (long)row * DMODEL))[tid];
  float ss = xv.x * xv.x + xv.y * xv.y + xv.z * xv.z + xv.w * xv.w;
#pragma unroll
  for (int o = 32; o > 0; o >>= 1) ss += __shfl_xor(ss, o);
  __shared__ float red[4];
  if ((tid & 63) == 0) red[tid >> 6] = ss;
  __syncthreads();
  const float tot = red[0] + red[1] + red[2] + red[3];
  const float s = rsqrtf(tot * (1.f / DMODEL) + RMS_EPS);
  if (invrms != nullptr && tid == 0) invrms[row] = s;
  const float4 wv = ((const float4*)w)[tid];
  ushort4 o4;
  o4.x = f2bf(xv.x * s * wv.x);
  o4.y = f2bf(xv.y * s * wv.y);
  o4.z = f2bf(xv.z * s * wv.z);
  o4.w = f2bf(xv.w * s * wv.w);
  ((ushort4*)(out + (long)row * DMODEL))[tid] = o4;
}

// ---- fold router weight through W_in: Wr2[e,k] = sum_j Wr[e,j]*nw[j]*W_in[j,k]
__global__ __launch_bounds__(256) void router_prep_kernel(
    const float* __restrict__ Wr, const float* __restrict__ nw,
    const float* __restrict__ W_in, float* __restrict__ Wr2) {
  __shared__ float wr[NEXP * DMODEL];  // 32 KB
  const int tid = threadIdx.x;
  for (int i = tid; i < NEXP * DMODEL; i += 256) wr[i] = Wr[i] * nw[i & (DMODEL - 1)];
  __syncthreads();
  const int kl = tid & 127;
  const int eb = (tid >> 7) * 4;
  const int kg = blockIdx.x * 128 + kl;
  float a0 = 0.f, a1 = 0.f, a2 = 0.f, a3 = 0.f;
  for (int j = 0; j < DMODEL; ++j) {
    const float wij = W_in[(long)j * DMODEL + kg];
    a0 += wr[(eb + 0) * DMODEL + j] * wij;
    a1 += wr[(eb + 1) * DMODEL + j] * wij;
    a2 += wr[(eb + 2) * DMODEL + j] * wij;
    a3 += wr[(eb + 3) * DMODEL + j] * wij;
  }
  Wr2[(eb + 0) * DMODEL + kg] = a0;
  Wr2[(eb + 1) * DMODEL + kg] = a1;
  Wr2[(eb + 2) * DMODEL + kg] = a2;
  Wr2[(eb + 3) * DMODEL + kg] = a3;
}

// ---- router: fp32 logits, top-2, softmax; scatter into compact lists ----
__global__ __launch_bounds__(64) void router_kernel(
    const float* __restrict__ x, const float* __restrict__ Wr2,
    const float* __restrict__ bias, const float* __restrict__ invrms,
    int* __restrict__ cnt, int* __restrict__ tok, float* __restrict__ gv) {
  const int row = blockIdx.x;
  const int lane = threadIdx.x;
  const float* xr = x + (long)row * DMODEL;
  float p[NEXP] = {0.f, 0.f, 0.f, 0.f, 0.f, 0.f, 0.f, 0.f};
  for (int k = lane; k < DMODEL; k += 64) {
    const float xv = xr[k];
#pragma unroll
    for (int e = 0; e < NEXP; ++e) p[e] += xv * Wr2[e * DMODEL + k];
  }
#pragma unroll
  for (int o = 32; o > 0; o >>= 1)
#pragma unroll
    for (int e = 0; e < NEXP; ++e) p[e] += __shfl_xor(p[e], o);
  if (lane == 0) {
    const float s = invrms[row];
    float logit[NEXP];
    float b0 = -1e30f, b1 = -1e30f;
    int i0 = 0, i1 = 0;
#pragma unroll
    for (int e = 0; e < NEXP; ++e) {
      logit[e] = p[e] * s;
      const float be = logit[e] + bias[e];
      if (be > b0)      { b1 = b0; i1 = i0; b0 = be; i0 = e; }
      else if (be > b1) { b1 = be; i1 = e; }
    }
    const float l0 = logit[i0], l1 = logit[i1];
    const float m = fmaxf(l0, l1);
    const float e0 = expf(l0 - m), e1 = expf(l1 - m);
    const float inv = 1.f / (e0 + e1);
    const int s0 = atomicAdd(&cnt[i0], 1);
    tok[i0 * NT + s0] = row;
    gv[i0 * NT + s0] = e0 * inv;
    const int s1 = atomicAdd(&cnt[i1], 1);
    tok[i1 * NT + s1] = row;
    gv[i1 * NT + s1] = e1 * inv;
  }
}

// ---- pad counts to 128-multiples, prefix-sum offsets, fill pad slots ----
__global__ __launch_bounds__(256) void pad_kernel(
    const int* __restrict__ cnt, int* __restrict__ tok,
    int* __restrict__ pcnt, int* __restrict__ off) {
  __shared__ int sc[NEXP], sp[NEXP];
  const int tid = threadIdx.x;
  if (tid == 0) {
    int o = 0;
    for (int e = 0; e < NEXP; ++e) {
      const int c = cnt[e];
      const int p = (c + 127) & ~127;
      sc[e] = c; sp[e] = p;
      pcnt[e] = p; off[e] = o;
      o += p;
    }
    off[NEXP] = o;
  }
  __syncthreads();
  for (int e = 0; e < NEXP; ++e) {
    const int c = sc[e], p = sp[e];
    for (int s = c + tid; s < p; s += 256) tok[e * NT + s] = 0;
  }
}

// ---- gather compact A rows: Ac[r] = hb[tok[r]] (pads copy row 0) ----
__global__ __launch_bounds__(256) void gather_kernel(
    const unsigned short* __restrict__ hb, const int* __restrict__ tok,
    const int* __restrict__ offs, unsigned short* __restrict__ Ac) {
  const int r = blockIdx.x;
  if (r >= offs[NEXP]) return;
  int e = 0;
#pragma unroll
  for (int i = 1; i < NEXP; ++i) e += (r >= offs[i]) ? 1 : 0;
  const int src = tok[e * NT + (r - offs[e])];
  const ushort4* s4 = (const ushort4*)(hb + (long)src * DMODEL);
  ushort4* d4 = (ushort4*)(Ac + (long)r * DMODEL);
  d4[threadIdx.x] = s4[threadIdx.x];
}

// ---- acc[tok[s]] += gv[s] * rmsnorm(oe[off+s])*enorm_w[e]  (one expert) ----
__global__ __launch_bounds__(256) void expert_scatter(
    const float* __restrict__ oe, const float* __restrict__ enw,
    const int* __restrict__ tok, const float* __restrict__ gv,
    const int* __restrict__ cnt, const int* __restrict__ off,
    int e, float* __restrict__ acc) {
  const int s = blockIdx.x;
  if (s >= cnt[e]) return;
  const int row = tok[e * NT + s];
  const float g = gv[e * NT + s];
  const int tid = threadIdx.x;
  const float4 xv = ((const float4*)(oe + ((long)off[e] + s) * DMODEL))[tid];
  float ss = xv.x * xv.x + xv.y * xv.y + xv.z * xv.z + xv.w * xv.w;
#pragma unroll
  for (int o = 32; o > 0; o >>= 1) ss += __shfl_xor(ss, o);
  __shared__ float red[4];
  if ((tid & 63) == 0) red[tid >> 6] = ss;
  __syncthreads();
  const float tot = red[0] + red[1] + red[2] + red[3];
  const float sc = rsqrtf(tot * (1.f / DMODEL) + RMS_EPS) * g;
  const float4 wv = ((const float4*)enw)[tid];
  float4* ap = (float4*)(acc + (long)row * DMODEL) + tid;
  float4 a = *ap;
  a.x += xv.x * sc * wv.x;
  a.y += xv.y * sc * wv.y;
  a.z += xv.z * sc * wv.z;
  a.w += xv.w * sc * wv.w;
  *ap = a;
}

extern "C" void kernel_launch(void* const* d_in, const int* in_sizes, int n_in,
                              void* d_out, int out_size, void* d_ws, size_t ws_size,
                              hipStream_t stream) {
  (void)in_sizes; (void)n_in; (void)out_size; (void)ws_size;
  const float* s_in  = (const float*)d_in[0];
  const float* W_in  = (const float*)d_in[1];
  const float* innw  = (const float*)d_in[2];
  const float* Wr    = (const float*)d_in[3];
  const float* ebias = (const float*)d_in[4];
  const float* Wg    = (const float*)d_in[5];
  const float* Wu    = (const float*)d_in[6];
  const float* Wd    = (const float*)d_in[7];
  const float* enw   = (const float*)d_in[8];
  const float* outnw = (const float*)d_in[9];
  const float* W_out = (const float*)d_in[10];
  float* out = (float*)d_out;

  // ---- workspace layout (~523 MB) ----
  char* base = (char*)d_ws;
  size_t off_b = 0;
  auto alloc = [&](size_t bytes) -> char* {
    char* p = base + off_b;
    off_b += (bytes + 255) & ~(size_t)255;
    return p;
  };
  unsigned short* xb    = (unsigned short*)alloc((size_t)NT * DMODEL * 2);
  unsigned short* Winb  = (unsigned short*)alloc((size_t)DMODEL * DMODEL * 2);
  unsigned short* Wgb   = (unsigned short*)alloc((size_t)NEXP * DFF * DMODEL * 2);
  unsigned short* Wub   = (unsigned short*)alloc((size_t)NEXP * DFF * DMODEL * 2);
  unsigned short* Wdb   = (unsigned short*)alloc((size_t)NEXP * DMODEL * DFF * 2);
  unsigned short* Woutb = (unsigned short*)alloc((size_t)DMODEL * DMODEL * 2);
  float*          hpre  = (float*)alloc((size_t)NT * DMODEL * 4);
  unsigned short* hb    = (unsigned short*)alloc((size_t)NT * DMODEL * 2);
  float*          invr  = (float*)alloc((size_t)NT * 4);
  float*          Wr2   = (float*)alloc((size_t)NEXP * DMODEL * 4);
  int*            cnt   = (int*)alloc((size_t)NEXP * 4);
  int*            pcnt  = (int*)alloc((size_t)NEXP * 4);
  int*            offs  = (int*)alloc((size_t)(NEXP + 1) * 4);
  int*            tok   = (int*)alloc((size_t)NEXP * NT * 4);
  float*          gv    = (float*)alloc((size_t)NEXP * NT * 4);
  unsigned short* Ac    = (unsigned short*)alloc((size_t)MAXROWS * DMODEL * 2);
  unsigned short* Hc    = (unsigned short*)alloc((size_t)MAXROWS * DFF * 2);
  float*          oec   = (float*)alloc((size_t)MAXROWS * DMODEL * 4);
  // aliases: accb over hpre (dead after rmsnorm), yb over xb (dead after
  // in-projection GEMM)
  float*          accb  = hpre;
  unsigned short* yb    = xb;

  // ---- 1. casts + zero the slot counters ----
  hipMemsetAsync(cnt, 0, NEXP * 4, stream);
  cast_bf16_kernel<<<2048, 256, 0, stream>>>(s_in, xb, (long)NT * DMODEL);
  cast_bf16_kernel<<<2048, 256, 0, stream>>>(W_in, Winb, (long)DMODEL * DMODEL);
  cast_bf16_kernel<<<2048, 256, 0, stream>>>(Wg, Wgb, (long)NEXP * DFF * DMODEL);
  cast_bf16_kernel<<<2048, 256, 0, stream>>>(Wu, Wub, (long)NEXP * DFF * DMODEL);
  cast_bf16_kernel<<<2048, 256, 0, stream>>>(Wd, Wdb, (long)NEXP * DMODEL * DFF);
  cast_bf16_kernel<<<2048, 256, 0, stream>>>(W_out, Woutb, (long)DMODEL * DMODEL);

  // ---- 2. hpre = x @ W_in^T ; hb = rmsnorm(hpre)*innw (+invrms) ----
  gemm_bt<0><<<dim3(NT / 128, DMODEL / 128), 256, 0, stream>>>(
      xb, Winb, hpre, NT, DMODEL, DMODEL);
  rmsnorm_kernel<<<NT, 256, 0, stream>>>(hpre, innw, hb, invr);
  hipMemsetAsync(accb, 0, (size_t)NT * DMODEL * 4, stream);

  // ---- 3. router + compaction ----
  router_prep_kernel<<<DMODEL / 128, 256, 0, stream>>>(Wr, innw, W_in, Wr2);
  router_kernel<<<NT, 64, 0, stream>>>(s_in, Wr2, ebias, invr, cnt, tok, gv);
  pad_kernel<<<1, 256, 0, stream>>>(cnt, tok, pcnt, offs);

  // ---- 4. gather compact A ----
  gather_kernel<<<MAXROWS, 256, 0, stream>>>(hb, tok, offs, Ac);

  // ---- 5/6. gate GEMM then up GEMM with in-place silu epilogue ----
  gemm_expert<1, 0><<<dim3(MAXROWS / 128, DFF / 128), 256, 0, stream>>>(
      Ac, Wgb, Hc, offs, DFF, DMODEL, (size_t)DFF * DMODEL);
  gemm_expert<1, 1><<<dim3(MAXROWS / 128, DFF / 128), 256, 0, stream>>>(
      Ac, Wub, Hc, offs, DFF, DMODEL, (size_t)DFF * DMODEL);

  // ---- 7. down projection (compact rows, f32 out) ----
  gemm_expert<0, 0><<<dim3(MAXROWS / 128, DMODEL / 128), 256, 0, stream>>>(
      Hc, Wdb, oec, offs, DMODEL, DFF, (size_t)DMODEL * DFF);

  // ---- 8. per-expert scatter-accumulate (sequential => deterministic) ----
  for (int e = 0; e < NEXP; ++e)
    expert_scatter<<<NT, 256, 0, stream>>>(
        oec, enw + (size_t)e * DMODEL, tok, gv, cnt, offs, e, accb);

  // ---- 9. output projection ----
  rmsnorm_kernel<<<NT, 256, 0, stream>>>(accb, outnw, yb, nullptr);
  gemm_bt<0><<<dim3(NT / 128, DMODEL / 128), 256, 0, stream>>>(
      yb, Woutb, out, NT, DMODEL, DMODEL);
}